// Round 1
// baseline (760.828 us; speedup 1.0000x reference)
//
#include <hip/hip_runtime.h>

constexpr int Lx = 8;
constexpr int Bx = 16;
constexpr int Dx = 512;
constexpr int Sx = 1500;
constexpr int Ex = 8;
constexpr int Kx = 1024;
constexpr int BS = Bx * Sx;          // 24000
#define EPSF 1e-12f

// ---------------- precompute: Wi = g*v/||v|| (norm over D), rows = L*E ----------------
__global__ __launch_bounds__(64) void k_wn_in(const float* __restrict__ v,
                                              const float* __restrict__ g,
                                              float* __restrict__ Wi) {
    int row = blockIdx.x;            // l*E + e
    int lane = threadIdx.x;          // 0..63
    const float* vr = v + row * Dx;
    float s = 0.f;
    for (int j = lane; j < Dx; j += 64) { float t = vr[j]; s += t * t; }
    for (int off = 32; off; off >>= 1) s += __shfl_down(s, off);
    s = __shfl(s, 0);
    float scale = g[row] / sqrtf(s);
    for (int j = lane; j < Dx; j += 64) Wi[row * Dx + j] = vr[j] * scale;
}

// ------------- precompute: Wo (norm over E), cn = l2norm(cb), cc = sum(cn^2) ----------
__global__ __launch_bounds__(256) void k_wn_out_cb(const float* __restrict__ ov,
                                                   const float* __restrict__ og,
                                                   const float* __restrict__ cb,
                                                   float* __restrict__ Wo,
                                                   float* __restrict__ cn,
                                                   float* __restrict__ cc) {
    int r = blockIdx.x * blockDim.x + threadIdx.x;
    if (r < Lx * Dx) {
        const float* vr = ov + r * Ex;
        float s = 0.f;
        for (int e = 0; e < Ex; e++) s += vr[e] * vr[e];
        float sc = og[r] / sqrtf(s);
        for (int e = 0; e < Ex; e++) Wo[r * Ex + e] = vr[e] * sc;
    } else {
        int q = r - Lx * Dx;
        if (q < Lx * Kx) {
            const float* vr = cb + q * Ex;
            float s = 0.f;
            for (int e = 0; e < Ex; e++) s += vr[e] * vr[e];
            float n = fmaxf(sqrtf(s), EPSF);
            float s2 = 0.f, qv[Ex];
            for (int e = 0; e < Ex; e++) { qv[e] = vr[e] / n; s2 += qv[e] * qv[e]; }
            for (int e = 0; e < Ex; e++) cn[q * Ex + e] = qv[e];
            cc[q] = s2;
        }
    }
}

// ----- stage normalized codebook into ws as float4 with XOR swizzle for LDS reads -----
// (we keep cn in [k][e] float layout in ws; swizzling happens on LDS store in k_vq)

// ---------------- init: xr (= out0 region) <- x ; zero loss accumulator ---------------
__global__ __launch_bounds__(256) void k_copyx(const float4* __restrict__ x,
                                               float4* __restrict__ xr,
                                               double* __restrict__ acc, unsigned n4) {
    unsigned i = blockIdx.x * blockDim.x + threadIdx.x;
    if (i == 0) *acc = 0.0;
    for (; i < n4; i += gridDim.x * blockDim.x) xr[i] = x[i];
}

// ---------------- A: x_proj[b,e,s] = sum_d Wi[e,d] * xr[b,d,s] + ib[e] ----------------
__global__ __launch_bounds__(256) void k_proj(const float* __restrict__ xr,
                                              const float* __restrict__ Wi,
                                              const float* __restrict__ ib,
                                              float* __restrict__ xproj, int l) {
    __shared__ float wi[Ex * Dx];        // 16 KB
    __shared__ float red[4 * Ex * 64];   // 8 KB
    const float* W = Wi + l * Ex * Dx;
    for (int i = threadIdx.x; i < Ex * Dx; i += 256) wi[i] = W[i];
    __syncthreads();
    int col = threadIdx.x & 63;
    int grp = threadIdx.x >> 6;
    int c = blockIdx.x * 64 + col;       // 0..23999
    int b = c / Sx, s = c % Sx;
    const float* xrb = xr + (size_t)b * Dx * Sx + s;
    float acc[Ex] = {0, 0, 0, 0, 0, 0, 0, 0};
    for (int d = grp * 128; d < grp * 128 + 128; d++) {
        float v = xrb[(size_t)d * Sx];
        #pragma unroll
        for (int e = 0; e < Ex; e++) acc[e] += wi[e * Dx + d] * v;
    }
    #pragma unroll
    for (int e = 0; e < Ex; e++) red[(grp * Ex + e) * 64 + col] = acc[e];
    __syncthreads();
    for (int o = threadIdx.x; o < Ex * 64; o += 256) {
        int e = o >> 6, cl = o & 63;
        float sum = red[(0 * Ex + e) * 64 + cl] + red[(1 * Ex + e) * 64 + cl] +
                    red[(2 * Ex + e) * 64 + cl] + red[(3 * Ex + e) * 64 + cl];
        int c2 = blockIdx.x * 64 + cl;
        int b2 = c2 / Sx, s2 = c2 % Sx;
        xproj[((size_t)b2 * Ex + e) * Sx + s2] = sum + ib[l * Ex + e];
    }
}

// ------- B: normalize, 1024 dots, logits write, argmax, gather xq, loss partial -------
__global__ __launch_bounds__(256) void k_vq(const float* __restrict__ xproj,
                                            const float* __restrict__ cn,
                                            const float* __restrict__ cc,
                                            const float* __restrict__ cb,
                                            float* __restrict__ logits,
                                            float* __restrict__ idxs,
                                            float* __restrict__ xq,
                                            double* __restrict__ acc, int l) {
    __shared__ float4 cnt4[Kx * 2];      // 32 KB, swizzled
    __shared__ float  ccs[Kx];           // 4 KB
    __shared__ float  bred[4];
    const float4* cn4 = (const float4*)(cn + (size_t)l * Kx * Ex);
    for (int i = threadIdx.x; i < Kx * 2; i += 256)
        cnt4[i ^ ((i >> 3) & 1)] = cn4[i];
    for (int i = threadIdx.x; i < Kx; i += 256) ccs[i] = cc[l * Kx + i];
    __syncthreads();
    int wave = threadIdx.x >> 6, lane = threadIdx.x & 63;
    float lossp = 0.f;
    for (int rr = 0; rr < 4; rr++) {
        int c = blockIdx.x * 16 + wave * 4 + rr;    // row 0..23999
        int b = c / Sx, s = c % Sx;
        float xp[Ex]; float xx2 = 0.f;
        #pragma unroll
        for (int e = 0; e < Ex; e++) {
            xp[e] = xproj[((size_t)b * Ex + e) * Sx + s];
            xx2 += xp[e] * xp[e];
        }
        float nrm = fmaxf(sqrtf(xx2), EPSF);
        float xn[Ex]; float xx = 0.f;
        #pragma unroll
        for (int e = 0; e < Ex; e++) { xn[e] = xp[e] / nrm; xx += xn[e] * xn[e]; }
        float* lrow = logits + ((size_t)c * Lx + l) * Kx;
        float best = -3.0e38f; int bk = 0;
        for (int j = 0; j < 16; j++) {
            int k = j * 64 + lane;
            float4 c0 = cnt4[(k * 2 + 0) ^ ((k >> 2) & 1)];
            float4 c1 = cnt4[(k * 2 + 1) ^ ((k >> 2) & 1)];
            float dot = xn[0] * c0.x + xn[1] * c0.y + xn[2] * c0.z + xn[3] * c0.w +
                        xn[4] * c1.x + xn[5] * c1.y + xn[6] * c1.z + xn[7] * c1.w;
            float lg = -(xx - 2.f * dot + ccs[k]);
            lrow[k] = lg;
            if (lg > best) { best = lg; bk = k; }
        }
        // wave argmax (max value; lowest k on exact tie -> np.argmax semantics)
        for (int off = 32; off; off >>= 1) {
            float ov = __shfl_xor(best, off);
            int   oi = __shfl_xor(bk, off);
            if (ov > best || (ov == best && oi < bk)) { best = ov; bk = oi; }
        }
        if (lane == 0) idxs[((size_t)b * Lx + l) * Sx + s] = (float)bk;
        const float* cbe = cb + ((size_t)l * Kx + bk) * Ex;
        if (lane < Ex) {
            float q = cbe[lane];
            xq[((size_t)b * Ex + lane) * Sx + s] = q;
            float dl = xp[lane] - q;
            lossp += dl * dl;
        }
    }
    for (int off = 32; off; off >>= 1) lossp += __shfl_down(lossp, off);
    if (lane == 0) bred[wave] = lossp;
    __syncthreads();
    if (threadIdx.x == 0) {
        float t = bred[0] + bred[1] + bred[2] + bred[3];
        atomicAdd(acc, (double)t);
    }
}

// --------- C: xr[b,d,s] -= (sum_e Wo[d,e]*xq[b,e,s] + ob[d])  (float4 over s) ---------
__global__ __launch_bounds__(256) void k_outproj(float* __restrict__ xr,
                                                 const float* __restrict__ xq,
                                                 const float* __restrict__ Wo,
                                                 const float* __restrict__ ob, int l) {
    const float* W   = Wo + l * Dx * Ex;
    const float* obl = ob + l * Dx;
    const unsigned S4 = Sx / 4;                 // 375
    const unsigned n4 = Bx * Dx * S4;           // 3,072,000
    for (unsigned i = blockIdx.x * blockDim.x + threadIdx.x; i < n4;
         i += gridDim.x * blockDim.x) {
        unsigned s4 = i % S4;
        unsigned bd = i / S4;
        unsigned d = bd % Dx;
        unsigned b = bd / Dx;
        float4 av = {0, 0, 0, 0};
        #pragma unroll
        for (int e = 0; e < Ex; e++) {
            float w = W[d * Ex + e];
            float4 q = *(const float4*)(xq + ((size_t)b * Ex + e) * Sx + s4 * 4);
            av.x += w * q.x; av.y += w * q.y; av.z += w * q.z; av.w += w * q.w;
        }
        float bias = obl[d];
        float4 r = *(const float4*)(xr + (size_t)bd * Sx + s4 * 4);
        r.x -= av.x + bias; r.y -= av.y + bias;
        r.z -= av.z + bias; r.w -= av.w + bias;
        *(float4*)(xr + (size_t)bd * Sx + s4 * 4) = r;
    }
}

// ---------------- final: out0 = x - xr (in place over out0) ; scalars -----------------
__global__ __launch_bounds__(256) void k_final(const float4* __restrict__ x,
                                               float4* __restrict__ out0,
                                               const double* __restrict__ acc,
                                               float* __restrict__ commit,
                                               float* __restrict__ cbl, unsigned n4) {
    unsigned i = blockIdx.x * blockDim.x + threadIdx.x;
    if (i == 0) {
        float v = (float)(*acc / (double)(Bx * Ex * Sx));
        *commit = v;
        *cbl = v;
    }
    for (; i < n4; i += gridDim.x * blockDim.x) {
        float4 a = x[i], b = out0[i];
        float4 o = {a.x - b.x, a.y - b.y, a.z - b.z, a.w - b.w};
        out0[i] = o;
    }
}

extern "C" void kernel_launch(void* const* d_in, const int* in_sizes, int n_in,
                              void* d_out, int out_size, void* d_ws, size_t ws_size,
                              hipStream_t stream) {
    const float* x     = (const float*)d_in[0];
    const float* in_v  = (const float*)d_in[1];
    const float* in_g  = (const float*)d_in[2];
    const float* in_b  = (const float*)d_in[3];
    const float* out_v = (const float*)d_in[4];
    const float* out_g = (const float*)d_in[5];
    const float* out_b = (const float*)d_in[6];
    const float* cb    = (const float*)d_in[7];

    float* out = (float*)d_out;
    float* xr       = out;                        // [B,D,S] doubles as xq_sum scratch
    float* oidx     = out + 12288000;             // [B,L,S]
    float* ologits  = out + 12480000;             // [B*S,L,K]
    float* ocommit  = out + 209088000;
    float* ocbl     = out + 209088001;

    char* w = (char*)d_ws;
    float*  Wi    = (float*)(w);                  // L*E*D   = 32768 f
    float*  Wo    = (float*)(w + 131072);         // L*D*E   = 32768 f
    float*  cn    = (float*)(w + 262144);         // L*K*E   = 65536 f
    float*  cc    = (float*)(w + 524288);         // L*K     = 8192 f
    float*  xproj = (float*)(w + 557056);         // B*E*S   = 192000 f
    float*  xq    = (float*)(w + 1325056);        // B*E*S   = 192000 f
    double* acc   = (double*)(w + 2093056);       // 1 d

    k_wn_in<<<Lx * Ex, 64, 0, stream>>>(in_v, in_g, Wi);
    k_wn_out_cb<<<(Lx * Dx + Lx * Kx) / 256, 256, 0, stream>>>(out_v, out_g, cb, Wo, cn, cc);
    k_copyx<<<2048, 256, 0, stream>>>((const float4*)x, (float4*)xr, acc, 3072000u);

    for (int l = 0; l < Lx; l++) {
        k_proj<<<BS / 64, 256, 0, stream>>>(xr, Wi, in_b, xproj, l);
        k_vq<<<BS / 16, 256, 0, stream>>>(xproj, cn, cc, cb, ologits, oidx, xq, acc, l);
        k_outproj<<<2048, 256, 0, stream>>>(xr, xq, Wo, out_b, l);
    }
    k_final<<<2048, 256, 0, stream>>>((const float4*)x, (float4*)xr, acc,
                                      ocommit, ocbl, 3072000u);
}